// Round 10
// baseline (341.531 us; speedup 1.0000x reference)
//
#include <hip/hip_runtime.h>

// ZooBP: atomic-free counting-sort CSR build + bf16 double-buffered gathers.
//  - Build: two-level LDS-histogram counting sort, zero global atomics.
//    NBLK=512 edge blocks; paper buckets dst>>10 (512 x 1024), authors src>>9.
//    BT=512 build blocks (16 waves/CU; R9 +21us).
//  - R10: scat_p+scat_a fused into scat_pa (ONE edge pass writes both staging
//    arrays); csr_p+csr_a+init fused into csr_all (paper buckets, author
//    buckets, and belief-init run concurrently in one launch).
//    S_p = d_out[0,16MB), S_a = d_out[16,32MB), ZpB = d_out[32,36MB).
//    (d_out 43.2MB written only in last iter; staging dead before that.)
//  - R5/R6 lessons (measured): NT stores = 3.4x write amplification; NT loads
//    = +10us gather (L1 bypass latency). NO non-temporal anything.
//  - R7 (kept): author adjacency split by dst-half; offA[2*NA+1]; author
//    gather walks half 0 then half 1 -> live Zp ~2MB, L2-resident.
//  - R10: author gather 8 threads/node (was 4) -> halves per-thread serial
//    latency rounds, doubles author-side TLP.
//  - adjacency entry = (idx<<13) | w13 (top 13 bits of fp32 w; exact for w=1).

static constexpr int   DD     = 18;
static constexpr int   DIMA   = 4;
static constexpr float CCF    = 0.01f;
static constexpr float SCALEF = 0.1f / 18.0f;
static constexpr int   PROP   = 5;

static constexpr int NBLK  = 512;          // edge-pass blocks
static constexpr int BT    = 512;          // build block threads
static constexpr int PSH   = 10;           // paper bucket shift (1024/bucket)
static constexpr int ASH   = 9;            // author bucket shift (512/bucket)
static constexpr int PBK   = 512;          // paper buckets
static constexpr int ABK   = 256;          // author buckets
static constexpr int PNB   = 1 << PSH;     // 1024 papers per bucket
static constexpr int ANB   = 1 << ASH;     // 512 authors per bucket
static constexpr int NBIN  = PBK + ABK;    // 768
static constexpr int NBINS = NBIN * NBLK;  // 393216 scan elements

__device__ __forceinline__ float bf2f(unsigned short u) {
    return __uint_as_float(((unsigned int)u) << 16);
}
__device__ __forceinline__ unsigned short f2bf(float f) {
    unsigned int x = __float_as_uint(f);
    return (unsigned short)((x + 0x7fffu + ((x >> 16) & 1u)) >> 16);
}
__device__ __forceinline__ unsigned int f2w13(float f) {
    unsigned int x = __float_as_uint(f);
    return ((x + 0x3ffffu + ((x >> 19) & 1u)) >> 19) & 0x1fffu;
}
__device__ __forceinline__ float w132f(unsigned int u) {
    return __uint_as_float(u << 19);
}
// XCD-aware: consecutive logical b share an XCD. NBLK%8==0.
__device__ __forceinline__ int swz_blk() {
    return ((int)blockIdx.x & 7) * (NBLK >> 3) + ((int)blockIdx.x >> 3);
}

// Pass A1: per-block LDS histograms over coarse buckets, both sides at once.
// bb layout: paper bin i -> bb[i*NBLK + b], author bin i -> bb[(PBK+i)*NBLK + b].
__global__ __launch_bounds__(BT) void count_bins(
    const int* __restrict__ esrc, const int* __restrict__ edst,
    int* __restrict__ bb, int E, int chunk)
{
    __shared__ int hP[PBK];
    __shared__ int hA[ABK];
    int t = threadIdx.x, b = swz_blk();
    if (t < PBK) hP[t] = 0;
    if (t < ABK) hA[t] = 0;
    __syncthreads();
    int beg = b * chunk;
    int end = beg + chunk; if (end > E) end = E;
    for (int e = beg + t; e < end; e += BT) {
        atomicAdd(&hP[edst[e] >> PSH], 1);
        atomicAdd(&hA[esrc[e] >> ASH], 1);
    }
    __syncthreads();
    if (t < PBK) bb[t * NBLK + b] = hP[t];
    if (t < ABK) bb[(PBK + t) * NBLK + b] = hA[t];
}

__global__ __launch_bounds__(256) void scan_block(
    int* __restrict__ off, int* __restrict__ bsum, int NT)
{
    __shared__ int s[256];
    int t = threadIdx.x;
    int i = blockIdx.x * 256 + t;
    int v = (i < NT) ? off[i] : 0;
    s[t] = v; __syncthreads();
    for (int dlt = 1; dlt < 256; dlt <<= 1) {
        int x = (t >= dlt) ? s[t - dlt] : 0;
        __syncthreads();
        s[t] += x;
        __syncthreads();
    }
    if (i < NT) off[i] = s[t] - v;
    if (t == 255) bsum[blockIdx.x] = s[255];
}

__global__ __launch_bounds__(256) void scan_tops(int* __restrict__ bsum, int nb)
{
    __shared__ int s[256];
    int t = threadIdx.x;
    int K = (nb + 255) / 256;
    int base = t * K;
    int sum = 0;
    for (int r = 0; r < K; ++r) { int idx = base + r; if (idx < nb) sum += bsum[idx]; }
    s[t] = sum; __syncthreads();
    for (int dlt = 1; dlt < 256; dlt <<= 1) {
        int x = (t >= dlt) ? s[t - dlt] : 0;
        __syncthreads();
        s[t] += x;
        __syncthreads();
    }
    int run = s[t] - sum;
    for (int r = 0; r < K; ++r) {
        int idx = base + r;
        if (idx < nb) { int tmp = bsum[idx]; bsum[idx] = run; run += tmp; }
    }
}

// Pass A3 fused: ONE edge pass scatters BOTH staging arrays.
// S_p record: {(src<<13)|w13, dst&(PNB-1)}.
// S_a record: {(dst<<13)|w13, ((src&(ANB-1))<<1)|(dst>=NP/2)}.
__global__ __launch_bounds__(BT) void scat_pa(
    const int* __restrict__ esrc, const int* __restrict__ edst,
    const float* __restrict__ w, const int* __restrict__ bb,
    const int* __restrict__ bsum,
    uint2* __restrict__ S_p, uint2* __restrict__ S_a,
    int E, int chunk, int NPH)
{
    __shared__ int baseP[PBK];
    __shared__ int baseA[ABK];
    int t = threadIdx.x, b = swz_blk();
    if (t < PBK) {
        int idx = t * NBLK + b;
        baseP[t] = bb[idx] + bsum[idx >> 8];
    }
    if (t < ABK) {
        int idx = (PBK + t) * NBLK + b;
        baseA[t] = bb[idx] + bsum[idx >> 8] - E;
    }
    __syncthreads();
    int beg = b * chunk;
    int end = beg + chunk; if (end > E) end = E;
    for (int e = beg + t; e < end; e += BT) {
        int d = edst[e], s = esrc[e];
        unsigned int w13 = f2w13(w[e]);
        int posP = atomicAdd(&baseP[d >> PSH], 1);
        S_p[posP] = make_uint2(((unsigned int)s << 13) | w13,
                               (unsigned int)(d & (PNB - 1)));
        unsigned int key = ((unsigned int)(s & (ANB - 1)) << 1) | (d >= NPH ? 1u : 0u);
        int posA = atomicAdd(&baseA[s >> ASH], 1);
        S_a[posA] = make_uint2(((unsigned int)d << 13) | w13, key);
    }
}

// Phase B fused: blocks [0,PBK) paper buckets (from S_p); [PBK,PBK+ABK)
// author buckets by (low<<1)|half key (from S_a) -> offA[2*NA+1];
// blocks [PBK+ABK,..) belief init.
__global__ __launch_bounds__(BT) void csr_all(
    const int* __restrict__ bb, const int* __restrict__ bsum,
    const uint2* __restrict__ S_p, const uint2* __restrict__ S_a,
    unsigned int* __restrict__ adjP, int* __restrict__ offP,
    unsigned int* __restrict__ adjA, int* __restrict__ offA,
    const int* __restrict__ mask_a, const int* __restrict__ lab_a,
    const int* __restrict__ mask_p, const int* __restrict__ lab_p,
    const float* __restrict__ Hpa,
    ushort4* __restrict__ Ya, ushort4* __restrict__ Zp,
    unsigned char* __restrict__ priorA, unsigned char* __restrict__ priorP,
    int NP, int NA, int NTot, int E)
{
    __shared__ int c[PNB];         // PNB == 2*ANB == 1024
    __shared__ int loc[PNB];
    __shared__ int ps[BT];
    if ((int)blockIdx.x < PBK) {
        // ---- paper bucket sort ----
        int t = threadIdx.x, b = blockIdx.x;
        int i0 = b * NBLK;
        int i1 = (b + 1) * NBLK;      // b=PBK-1 -> author-region start prefix = E
        int sbeg = bb[i0] + bsum[i0 >> 8];
        int send = bb[i1] + bsum[i1 >> 8];
        for (int i = t; i < PNB; i += BT) c[i] = 0;
        __syncthreads();
        for (int i = sbeg + t; i < send; i += BT)
            atomicAdd(&c[S_p[i].y], 1);
        __syncthreads();
        int a0 = c[2 * t], a1 = c[2 * t + 1];
        ps[t] = a0 + a1; __syncthreads();
        for (int dlt = 1; dlt < BT; dlt <<= 1) {
            int x = (t >= dlt) ? ps[t - dlt] : 0;
            __syncthreads();
            ps[t] += x;
            __syncthreads();
        }
        int run = ps[t] - a0 - a1;     // exclusive within bucket
        int n0 = (b << PSH) + 2 * t;
        loc[2 * t] = run;
        loc[2 * t + 1] = run + a0;
        if (n0 < NP)     offP[n0]     = sbeg + run;
        if (n0 + 1 < NP) offP[n0 + 1] = sbeg + run + a0;
        if (b == 0 && t == 0) offP[NP] = E;
        __syncthreads();
        for (int i = sbeg + t; i < send; i += BT) {
            uint2 r = S_p[i];
            int p = atomicAdd(&loc[r.y], 1);
            adjP[sbeg + p] = r.x;
        }
    } else if ((int)blockIdx.x < PBK + ABK) {
        // ---- author bucket sort ----
        int t = threadIdx.x, b = (int)blockIdx.x - PBK;
        int x0 = (PBK + b) * NBLK;
        int sbeg = bb[x0] + bsum[x0 >> 8] - E;
        int send;
        if (b == ABK - 1) send = E;    // x0+NBLK would be NBINS (unscanned)
        else { int x1 = x0 + NBLK; send = bb[x1] + bsum[x1 >> 8] - E; }
        for (int i = t; i < 2 * ANB; i += BT) c[i] = 0;
        __syncthreads();
        for (int i = sbeg + t; i < send; i += BT)
            atomicAdd(&c[S_a[i].y], 1);
        __syncthreads();
        int a0 = c[2 * t], a1 = c[2 * t + 1];
        ps[t] = a0 + a1; __syncthreads();
        for (int dlt = 1; dlt < BT; dlt <<= 1) {
            int x = (t >= dlt) ? ps[t - dlt] : 0;
            __syncthreads();
            ps[t] += x;
            __syncthreads();
        }
        int run = ps[t] - a0 - a1;     // exclusive within bucket
        int n0 = (b << (ASH + 1)) + 2 * t;
        loc[2 * t] = run;
        loc[2 * t + 1] = run + a0;
        if (n0 < 2 * NA)     offA[n0]     = sbeg + run;
        if (n0 + 1 < 2 * NA) offA[n0 + 1] = sbeg + run + a0;
        if (b == 0 && t == 0) offA[2 * NA] = E;
        __syncthreads();
        for (int i = sbeg + t; i < send; i += BT) {
            uint2 r = S_a[i];
            int p = atomicAdd(&loc[r.y], 1);
            adjA[sbeg + p] = r.x;
        }
    } else {
        // ---- belief init ----
        __shared__ float sH[72], sCol[4];
        int t = threadIdx.x;
        if (t < 72) sH[t] = Hpa[(t >> 2) * DD + (t & 3)];
        if (t < 4) { float s = 0.f; for (int k = 0; k < DD; ++k) s += Hpa[k * DD + t]; sCol[t] = s; }
        __syncthreads();
        int i = ((int)blockIdx.x - PBK - ABK) * BT + t;
        if (i >= NTot) return;
        if (i < NA) {
            float x[4] = {0.f, 0.f, 0.f, 0.f};
            int m = mask_a[i];
            int l = m ? lab_a[i] : 0;
            if (m) {
                x[0] = x[1] = x[2] = x[3] = -CCF;
                x[l] += (float)DIMA * CCF;
            }
            priorA[i] = m ? (unsigned char)(0x20 | l) : 0;
            Ya[i] = make_ushort4(f2bf(x[0]), f2bf(x[1]), f2bf(x[2]), f2bf(x[3]));
        } else {
            int d = i - NA;
            float z0 = 0.f, z1 = 0.f, z2 = 0.f, z3 = 0.f;
            int m = mask_p[d];
            int l = m ? lab_p[d] : 0;
            if (m) {
                float lb = (float)DD * CCF;
                z0 = -CCF * sCol[0] + lb * sH[l * 4 + 0];
                z1 = -CCF * sCol[1] + lb * sH[l * 4 + 1];
                z2 = -CCF * sCol[2] + lb * sH[l * 4 + 2];
                z3 = -CCF * sCol[3] + lb * sH[l * 4 + 3];
            }
            priorP[d] = m ? (unsigned char)(0x20 | l) : 0;
            Zp[d] = make_ushort4(f2bf(z0), f2bf(z1), f2bf(z2), f2bf(z3));
        }
    }
}

// One fused Jacobi step. Papers: ZpNew = z0 + (gather YaOld) @ M.
// Authors (8 thr/node): YaNew = x0 + SCALEF * (gather ZpOld), dst-half 0
// then 1 so the live Zp working set is ~2MB (L2-resident per XCD).
// ZpNew store skipped on last iter (ZpB lives in d_out).
__global__ __launch_bounds__(256) void gather_iter(
    const int* __restrict__ offP, const int* __restrict__ offA,
    const unsigned int* __restrict__ adjP, const unsigned int* __restrict__ adjA,
    const ushort4* __restrict__ ZpOld, ushort4* __restrict__ ZpNew,
    const ushort4* __restrict__ YaOld, ushort4* __restrict__ YaNew,
    const unsigned char* __restrict__ priorA, const unsigned char* __restrict__ priorP,
    const float* __restrict__ Hap, const float* __restrict__ Hpa,
    float* __restrict__ out, int NP, int NA, int last, int gpB)
{
    if ((int)blockIdx.x < gpB) {
        // ---- papers ----
        __shared__ float sH[72], sCol[4], sM[16], sHap[72];
        int t = threadIdx.x;
        if (t < 72) sH[t] = Hpa[(t >> 2) * DD + (t & 3)];
        if (t < 4) { float s = 0.f; for (int k = 0; k < DD; ++k) s += Hpa[k * DD + t]; sCol[t] = s; }
        if (t < 16) { int i = t >> 2, j = t & 3; float s = 0.f;
                      for (int k = 0; k < DD; ++k) s += Hap[i * DD + k] * Hpa[k * DD + j];
                      sM[t] = SCALEF * s; }
        if (t < 72) sHap[t] = SCALEF * Hap[t];
        __syncthreads();

        int d = (int)blockIdx.x * 256 + t;
        if (d >= NP) return;
        int beg = offP[d], end = offP[d + 1];
        unsigned int pb = priorP[d];   // hoisted off the critical-path tail
        float ax = 0.f, ay = 0.f, az = 0.f, aw = 0.f;
        int s = beg;
        for (; s + 8 <= end; s += 8) {
            unsigned int e0 = adjP[s],     e1 = adjP[s + 1], e2 = adjP[s + 2], e3 = adjP[s + 3];
            unsigned int e4 = adjP[s + 4], e5 = adjP[s + 5], e6 = adjP[s + 6], e7 = adjP[s + 7];
            ushort4 y0 = YaOld[e0 >> 13], y1 = YaOld[e1 >> 13];
            ushort4 y2 = YaOld[e2 >> 13], y3 = YaOld[e3 >> 13];
            ushort4 y4 = YaOld[e4 >> 13], y5 = YaOld[e5 >> 13];
            ushort4 y6 = YaOld[e6 >> 13], y7 = YaOld[e7 >> 13];
            float w0 = w132f(e0 & 0x1fffu), w1 = w132f(e1 & 0x1fffu);
            float w2 = w132f(e2 & 0x1fffu), w3 = w132f(e3 & 0x1fffu);
            float w4 = w132f(e4 & 0x1fffu), w5 = w132f(e5 & 0x1fffu);
            float w6 = w132f(e6 & 0x1fffu), w7 = w132f(e7 & 0x1fffu);
            ax += w0 * bf2f(y0.x) + w1 * bf2f(y1.x) + w2 * bf2f(y2.x) + w3 * bf2f(y3.x)
                + w4 * bf2f(y4.x) + w5 * bf2f(y5.x) + w6 * bf2f(y6.x) + w7 * bf2f(y7.x);
            ay += w0 * bf2f(y0.y) + w1 * bf2f(y1.y) + w2 * bf2f(y2.y) + w3 * bf2f(y3.y)
                + w4 * bf2f(y4.y) + w5 * bf2f(y5.y) + w6 * bf2f(y6.y) + w7 * bf2f(y7.y);
            az += w0 * bf2f(y0.z) + w1 * bf2f(y1.z) + w2 * bf2f(y2.z) + w3 * bf2f(y3.z)
                + w4 * bf2f(y4.z) + w5 * bf2f(y5.z) + w6 * bf2f(y6.z) + w7 * bf2f(y7.z);
            aw += w0 * bf2f(y0.w) + w1 * bf2f(y1.w) + w2 * bf2f(y2.w) + w3 * bf2f(y3.w)
                + w4 * bf2f(y4.w) + w5 * bf2f(y5.w) + w6 * bf2f(y6.w) + w7 * bf2f(y7.w);
        }
        for (; s + 4 <= end; s += 4) {
            unsigned int e0 = adjP[s], e1 = adjP[s + 1], e2 = adjP[s + 2], e3 = adjP[s + 3];
            ushort4 y0 = YaOld[e0 >> 13], y1 = YaOld[e1 >> 13];
            ushort4 y2 = YaOld[e2 >> 13], y3 = YaOld[e3 >> 13];
            float w0 = w132f(e0 & 0x1fffu), w1 = w132f(e1 & 0x1fffu);
            float w2 = w132f(e2 & 0x1fffu), w3 = w132f(e3 & 0x1fffu);
            ax += w0 * bf2f(y0.x) + w1 * bf2f(y1.x) + w2 * bf2f(y2.x) + w3 * bf2f(y3.x);
            ay += w0 * bf2f(y0.y) + w1 * bf2f(y1.y) + w2 * bf2f(y2.y) + w3 * bf2f(y3.y);
            az += w0 * bf2f(y0.z) + w1 * bf2f(y1.z) + w2 * bf2f(y2.z) + w3 * bf2f(y3.z);
            aw += w0 * bf2f(y0.w) + w1 * bf2f(y1.w) + w2 * bf2f(y2.w) + w3 * bf2f(y3.w);
        }
        for (; s < end; ++s) {
            unsigned int ent = adjP[s];
            float wt = w132f(ent & 0x1fffu);
            ushort4 yv = YaOld[ent >> 13];
            ax += wt * bf2f(yv.x); ay += wt * bf2f(yv.y);
            az += wt * bf2f(yv.z); aw += wt * bf2f(yv.w);
        }
        int l = pb & 31;
        float base = pb ? -CCF : 0.f;
        float lb   = pb ? (float)DD * CCF : 0.f;
        if (!last) {
            float z0 = base * sCol[0] + lb * sH[l * 4 + 0] + ax * sM[0] + ay * sM[4] + az * sM[8]  + aw * sM[12];
            float z1 = base * sCol[1] + lb * sH[l * 4 + 1] + ax * sM[1] + ay * sM[5] + az * sM[9]  + aw * sM[13];
            float z2 = base * sCol[2] + lb * sH[l * 4 + 2] + ax * sM[2] + ay * sM[6] + az * sM[10] + aw * sM[14];
            float z3 = base * sCol[3] + lb * sH[l * 4 + 3] + ax * sM[3] + ay * sM[7] + az * sM[11] + aw * sM[15];
            ZpNew[d] = make_ushort4(f2bf(z0), f2bf(z1), f2bf(z2), f2bf(z3));
        } else {
            float* row = out + (size_t)(NA + d) * DD;
#pragma unroll
            for (int j = 0; j < DD; ++j) {
                row[j] = base + ((j == l) ? lb : 0.f)
                       + ax * sHap[0 * DD + j] + ay * sHap[1 * DD + j]
                       + az * sHap[2 * DD + j] + aw * sHap[3 * DD + j];
            }
        }
    } else {
        // ---- authors: 8 threads per node, dst-half 0 then 1, unroll x2 ----
        int tid = ((int)blockIdx.x - gpB) * 256 + threadIdx.x;
        int a = tid >> 3, sub = tid & 7;
        if (a >= NA) return;
        int beg = offA[2 * a], mid = offA[2 * a + 1], end = offA[2 * a + 2];
        unsigned int pb = priorA[a];   // hoisted (uniform per node, L2 hit)
        float ax = 0.f, ay = 0.f, az = 0.f, aw = 0.f;
#pragma unroll
        for (int h = 0; h < 2; ++h) {
            int lo = h ? mid : beg;
            int hi = h ? end : mid;
            int s = lo + sub;
            for (; s + 8 < hi; s += 16) {
                unsigned int e0 = adjA[s], e1 = adjA[s + 8];
                ushort4 z0 = ZpOld[e0 >> 13], z1 = ZpOld[e1 >> 13];
                float w0 = w132f(e0 & 0x1fffu), w1 = w132f(e1 & 0x1fffu);
                ax += w0 * bf2f(z0.x) + w1 * bf2f(z1.x);
                ay += w0 * bf2f(z0.y) + w1 * bf2f(z1.y);
                az += w0 * bf2f(z0.z) + w1 * bf2f(z1.z);
                aw += w0 * bf2f(z0.w) + w1 * bf2f(z1.w);
            }
            for (; s < hi; s += 8) {
                unsigned int ent = adjA[s];
                float wt = w132f(ent & 0x1fffu);
                ushort4 z = ZpOld[ent >> 13];
                ax += wt * bf2f(z.x); ay += wt * bf2f(z.y);
                az += wt * bf2f(z.z); aw += wt * bf2f(z.w);
            }
        }
        ax += __shfl_xor(ax, 1); ay += __shfl_xor(ay, 1);
        az += __shfl_xor(az, 1); aw += __shfl_xor(aw, 1);
        ax += __shfl_xor(ax, 2); ay += __shfl_xor(ay, 2);
        az += __shfl_xor(az, 2); aw += __shfl_xor(aw, 2);
        ax += __shfl_xor(ax, 4); ay += __shfl_xor(ay, 4);
        az += __shfl_xor(az, 4); aw += __shfl_xor(aw, 4);
        if (sub == 0) {
            int l = pb & 31;
            float x0 = pb ? ((l == 0) ? ((float)DIMA - 1.f) * CCF : -CCF) : 0.f;
            float x1 = pb ? ((l == 1) ? ((float)DIMA - 1.f) * CCF : -CCF) : 0.f;
            float x2 = pb ? ((l == 2) ? ((float)DIMA - 1.f) * CCF : -CCF) : 0.f;
            float x3 = pb ? ((l == 3) ? ((float)DIMA - 1.f) * CCF : -CCF) : 0.f;
            float y0 = x0 + SCALEF * ax, y1 = x1 + SCALEF * ay;
            float y2 = x2 + SCALEF * az, y3 = x3 + SCALEF * aw;
            YaNew[a] = make_ushort4(f2bf(y0), f2bf(y1), f2bf(y2), f2bf(y3));
            if (last) {
                float* row = out + (size_t)a * DD;
                row[0] = y0; row[1] = y1; row[2] = y2; row[3] = y3;
#pragma unroll
                for (int j = DIMA; j < DD; ++j) row[j] = 0.f;
            }
        }
    }
}

extern "C" void kernel_launch(void* const* d_in, const int* in_sizes, int n_in,
                              void* d_out, int out_size, void* d_ws, size_t ws_size,
                              hipStream_t stream)
{
    const float* H_ap   = (const float*)d_in[0];
    const float* H_pa   = (const float*)d_in[1];
    const float* w      = (const float*)d_in[2];
    const int*   esrc   = (const int*)d_in[3];
    const int*   edst   = (const int*)d_in[4];
    const int*   mask_a = (const int*)d_in[5];
    const int*   lab_a  = (const int*)d_in[6];
    const int*   mask_p = (const int*)d_in[7];
    const int*   lab_p  = (const int*)d_in[8];

    const int E  = in_sizes[2];
    const int NA = in_sizes[5];
    const int NP = in_sizes[7];
    const int NT = NP + NA;
    const int NPH = NP / 2;

    // workspace (~26.6 MB)
    char*  basep = (char*)d_ws;
    size_t o = 0;
    auto alloc = [&](size_t bytes) -> char* {
        o = (o + 15) & ~(size_t)15;
        char* p = basep + o;
        o += bytes;
        return p;
    };
    int*           offP   = (int*)          alloc((size_t)(NP + 1) * sizeof(int));
    int*           offA   = (int*)          alloc((size_t)(2 * NA + 1) * sizeof(int));
    int*           bb     = (int*)          alloc((size_t)(NBINS + 1) * sizeof(int));
    int*           bsum   = (int*)          alloc((size_t)4096 * sizeof(int));
    unsigned int*  adjP   = (unsigned int*) alloc((size_t)E * sizeof(unsigned int));
    unsigned int*  adjA   = (unsigned int*) alloc((size_t)E * sizeof(unsigned int));
    unsigned char* priorP = (unsigned char*)alloc((size_t)NP);
    unsigned char* priorA = (unsigned char*)alloc((size_t)NA);
    ushort4*       YaA    = (ushort4*)      alloc((size_t)NA * sizeof(ushort4));
    ushort4*       YaB    = (ushort4*)      alloc((size_t)NA * sizeof(ushort4));
    ushort4*       ZpA    = (ushort4*)      alloc((size_t)NP * sizeof(ushort4));
    (void)ws_size;

    // S_p (16MB), S_a (16MB), ZpB (4MB) live in d_out (43.2MB): out is
    // written only in the last iteration. Staging dead after csr_all; ZpB
    // written it0/it2, last read it3; ZpNew store skipped when last.
    float*   out = (float*)d_out;
    size_t   sBytes = (((size_t)E * sizeof(uint2)) + 255) & ~(size_t)255;
    uint2*   S_p = (uint2*)d_out;
    uint2*   S_a = (uint2*)((char*)d_out + sBytes);
    ushort4* ZpB = (ushort4*)((char*)d_out + 2 * sBytes);

    ushort4* YaBuf[2] = {YaA, YaB};
    ushort4* ZpBuf[2] = {ZpA, ZpB};

    const int chunk = (E + NBLK - 1) / NBLK;
    const int gp    = (NP + 255) / 256;
    const int ga8   = (NA * 8 + 255) / 256;
    const int gni   = (NT + BT - 1) / BT;
    const int nb    = (NBINS + 255) / 256;        // 1536

    count_bins<<<NBLK, BT, 0, stream>>>(esrc, edst, bb, E, chunk);
    scan_block<<<nb, 256, 0, stream>>>(bb, bsum, NBINS);
    scan_tops<<<1, 256, 0, stream>>>(bsum, nb);
    scat_pa<<<NBLK, BT, 0, stream>>>(esrc, edst, w, bb, bsum, S_p, S_a,
                                     E, chunk, NPH);
    csr_all<<<PBK + ABK + gni, BT, 0, stream>>>(bb, bsum, S_p, S_a,
                                                adjP, offP, adjA, offA,
                                                mask_a, lab_a, mask_p, lab_p,
                                                H_pa, YaA, ZpA, priorA, priorP,
                                                NP, NA, NT, E);

    for (int it = 0; it < PROP; ++it) {
        int last = (it == PROP - 1) ? 1 : 0;
        int cur = it & 1, nxt = 1 - cur;
        gather_iter<<<gp + ga8, 256, 0, stream>>>(offP, offA, adjP, adjA,
                                                  ZpBuf[cur], ZpBuf[nxt],
                                                  YaBuf[cur], YaBuf[nxt],
                                                  priorA, priorP,
                                                  H_ap, H_pa, out,
                                                  NP, NA, last, gp);
    }
}

// Round 11
// 331.937 us; speedup vs baseline: 1.0289x; 1.0289x over previous
//
#include <hip/hip_runtime.h>

// ZooBP: atomic-free counting-sort CSR build + bf16 double-buffered gathers.
//  - Build: two-level LDS-histogram counting sort, zero global atomics.
//    NBLK=512 edge blocks; paper buckets dst>>10 (512 x 1024), authors src>>9.
//    BT=512 build blocks (16 waves/CU; R9 +21us).
//  - R10 lesson (measured): FUSED scat_pa interleaving stores into two 16MB
//    staging regions = 3x write amplification (94MB vs 32MB ideal, 58us).
//    KEEP scats as two serial single-region passes; KEEP csr_all fusion
//    (paper-sort || author-sort || init in one launch — never in top-5).
//  - S_p = d_out[0,16MB), S_a = d_out[16,32MB), ZpB = d_out[32,36MB).
//    (d_out 43.2MB written only in last iter; staging dead after csr_all.)
//  - R5/R6 lessons (measured): NT stores = 3.4x write amplification; NT loads
//    = +10us gather (L1 bypass latency). NO non-temporal anything.
//  - R7 (kept): author adjacency split by dst-half; offA[2*NA+1]; author
//    gather walks half 0 then half 1 -> live Zp ~2MB, L2-resident.
//  - R11: authors back to 4 thr/node (R10's 8 thr/node was neutral-negative).
//  - adjacency entry = (idx<<13) | w13 (top 13 bits of fp32 w; exact for w=1).

static constexpr int   DD     = 18;
static constexpr int   DIMA   = 4;
static constexpr float CCF    = 0.01f;
static constexpr float SCALEF = 0.1f / 18.0f;
static constexpr int   PROP   = 5;

static constexpr int NBLK  = 512;          // edge-pass blocks
static constexpr int BT    = 512;          // build block threads
static constexpr int PSH   = 10;           // paper bucket shift (1024/bucket)
static constexpr int ASH   = 9;            // author bucket shift (512/bucket)
static constexpr int PBK   = 512;          // paper buckets
static constexpr int ABK   = 256;          // author buckets
static constexpr int PNB   = 1 << PSH;     // 1024 papers per bucket
static constexpr int ANB   = 1 << ASH;     // 512 authors per bucket
static constexpr int NBIN  = PBK + ABK;    // 768
static constexpr int NBINS = NBIN * NBLK;  // 393216 scan elements

__device__ __forceinline__ float bf2f(unsigned short u) {
    return __uint_as_float(((unsigned int)u) << 16);
}
__device__ __forceinline__ unsigned short f2bf(float f) {
    unsigned int x = __float_as_uint(f);
    return (unsigned short)((x + 0x7fffu + ((x >> 16) & 1u)) >> 16);
}
__device__ __forceinline__ unsigned int f2w13(float f) {
    unsigned int x = __float_as_uint(f);
    return ((x + 0x3ffffu + ((x >> 19) & 1u)) >> 19) & 0x1fffu;
}
__device__ __forceinline__ float w132f(unsigned int u) {
    return __uint_as_float(u << 19);
}
// XCD-aware: consecutive logical b share an XCD. NBLK%8==0.
__device__ __forceinline__ int swz_blk() {
    return ((int)blockIdx.x & 7) * (NBLK >> 3) + ((int)blockIdx.x >> 3);
}

// Pass A1: per-block LDS histograms over coarse buckets, both sides at once.
// bb layout: paper bin i -> bb[i*NBLK + b], author bin i -> bb[(PBK+i)*NBLK + b].
__global__ __launch_bounds__(BT) void count_bins(
    const int* __restrict__ esrc, const int* __restrict__ edst,
    int* __restrict__ bb, int E, int chunk)
{
    __shared__ int hP[PBK];
    __shared__ int hA[ABK];
    int t = threadIdx.x, b = swz_blk();
    if (t < PBK) hP[t] = 0;
    if (t < ABK) hA[t] = 0;
    __syncthreads();
    int beg = b * chunk;
    int end = beg + chunk; if (end > E) end = E;
    for (int e = beg + t; e < end; e += BT) {
        atomicAdd(&hP[edst[e] >> PSH], 1);
        atomicAdd(&hA[esrc[e] >> ASH], 1);
    }
    __syncthreads();
    if (t < PBK) bb[t * NBLK + b] = hP[t];
    if (t < ABK) bb[(PBK + t) * NBLK + b] = hA[t];
}

__global__ __launch_bounds__(256) void scan_block(
    int* __restrict__ off, int* __restrict__ bsum, int NT)
{
    __shared__ int s[256];
    int t = threadIdx.x;
    int i = blockIdx.x * 256 + t;
    int v = (i < NT) ? off[i] : 0;
    s[t] = v; __syncthreads();
    for (int dlt = 1; dlt < 256; dlt <<= 1) {
        int x = (t >= dlt) ? s[t - dlt] : 0;
        __syncthreads();
        s[t] += x;
        __syncthreads();
    }
    if (i < NT) off[i] = s[t] - v;
    if (t == 255) bsum[blockIdx.x] = s[255];
}

__global__ __launch_bounds__(256) void scan_tops(int* __restrict__ bsum, int nb)
{
    __shared__ int s[256];
    int t = threadIdx.x;
    int K = (nb + 255) / 256;
    int base = t * K;
    int sum = 0;
    for (int r = 0; r < K; ++r) { int idx = base + r; if (idx < nb) sum += bsum[idx]; }
    s[t] = sum; __syncthreads();
    for (int dlt = 1; dlt < 256; dlt <<= 1) {
        int x = (t >= dlt) ? s[t - dlt] : 0;
        __syncthreads();
        s[t] += x;
        __syncthreads();
    }
    int run = s[t] - sum;
    for (int r = 0; r < K; ++r) {
        int idx = base + r;
        if (idx < nb) { int tmp = bsum[idx]; bsum[idx] = run; run += tmp; }
    }
}

// Pass A3 (papers): scatter staging records using LDS ranks on scanned bases.
// Global exclusive prefix of flat idx = bb[idx] + bsum[idx>>8].
__global__ __launch_bounds__(BT) void scat_p(
    const int* __restrict__ esrc, const int* __restrict__ edst,
    const float* __restrict__ w, const int* __restrict__ bb,
    const int* __restrict__ bsum, uint2* __restrict__ S, int E, int chunk)
{
    __shared__ int base[PBK];
    int t = threadIdx.x, b = swz_blk();
    if (t < PBK) {
        int idx = t * NBLK + b;
        base[t] = bb[idx] + bsum[idx >> 8];
    }
    __syncthreads();
    int beg = b * chunk;
    int end = beg + chunk; if (end > E) end = E;
    for (int e = beg + t; e < end; e += BT) {
        int d = edst[e], s = esrc[e];
        unsigned int rec = ((unsigned int)s << 13) | f2w13(w[e]);
        int pos = atomicAdd(&base[d >> PSH], 1);
        S[pos] = make_uint2(rec, (unsigned int)(d & (PNB - 1)));
    }
}

// Pass A3 (authors): record.x = adjA word (dst<<13|w13),
// record.y = ((src&(ANB-1))<<1) | (dst >= NP/2)  -- dst-half split key.
__global__ __launch_bounds__(BT) void scat_a(
    const int* __restrict__ esrc, const int* __restrict__ edst,
    const float* __restrict__ w, const int* __restrict__ bb,
    const int* __restrict__ bsum, uint2* __restrict__ S, int E, int chunk,
    int NPH)
{
    __shared__ int base[ABK];
    int t = threadIdx.x, b = swz_blk();
    if (t < ABK) {
        int idx = (PBK + t) * NBLK + b;
        base[t] = bb[idx] + bsum[idx >> 8] - E;
    }
    __syncthreads();
    int beg = b * chunk;
    int end = beg + chunk; if (end > E) end = E;
    for (int e = beg + t; e < end; e += BT) {
        int d = edst[e], s = esrc[e];
        unsigned int rec = ((unsigned int)d << 13) | f2w13(w[e]);
        unsigned int key = ((unsigned int)(s & (ANB - 1)) << 1) | (d >= NPH ? 1u : 0u);
        int pos = atomicAdd(&base[s >> ASH], 1);
        S[pos] = make_uint2(rec, key);
    }
}

// Phase B fused: blocks [0,PBK) paper buckets (from S_p); [PBK,PBK+ABK)
// author buckets by (low<<1)|half key (from S_a) -> offA[2*NA+1];
// blocks [PBK+ABK,..) belief init.
__global__ __launch_bounds__(BT) void csr_all(
    const int* __restrict__ bb, const int* __restrict__ bsum,
    const uint2* __restrict__ S_p, const uint2* __restrict__ S_a,
    unsigned int* __restrict__ adjP, int* __restrict__ offP,
    unsigned int* __restrict__ adjA, int* __restrict__ offA,
    const int* __restrict__ mask_a, const int* __restrict__ lab_a,
    const int* __restrict__ mask_p, const int* __restrict__ lab_p,
    const float* __restrict__ Hpa,
    ushort4* __restrict__ Ya, ushort4* __restrict__ Zp,
    unsigned char* __restrict__ priorA, unsigned char* __restrict__ priorP,
    int NP, int NA, int NTot, int E)
{
    __shared__ int c[PNB];         // PNB == 2*ANB == 1024
    __shared__ int loc[PNB];
    __shared__ int ps[BT];
    if ((int)blockIdx.x < PBK) {
        // ---- paper bucket sort ----
        int t = threadIdx.x, b = blockIdx.x;
        int i0 = b * NBLK;
        int i1 = (b + 1) * NBLK;      // b=PBK-1 -> author-region start prefix = E
        int sbeg = bb[i0] + bsum[i0 >> 8];
        int send = bb[i1] + bsum[i1 >> 8];
        for (int i = t; i < PNB; i += BT) c[i] = 0;
        __syncthreads();
        for (int i = sbeg + t; i < send; i += BT)
            atomicAdd(&c[S_p[i].y], 1);
        __syncthreads();
        int a0 = c[2 * t], a1 = c[2 * t + 1];
        ps[t] = a0 + a1; __syncthreads();
        for (int dlt = 1; dlt < BT; dlt <<= 1) {
            int x = (t >= dlt) ? ps[t - dlt] : 0;
            __syncthreads();
            ps[t] += x;
            __syncthreads();
        }
        int run = ps[t] - a0 - a1;     // exclusive within bucket
        int n0 = (b << PSH) + 2 * t;
        loc[2 * t] = run;
        loc[2 * t + 1] = run + a0;
        if (n0 < NP)     offP[n0]     = sbeg + run;
        if (n0 + 1 < NP) offP[n0 + 1] = sbeg + run + a0;
        if (b == 0 && t == 0) offP[NP] = E;
        __syncthreads();
        for (int i = sbeg + t; i < send; i += BT) {
            uint2 r = S_p[i];
            int p = atomicAdd(&loc[r.y], 1);
            adjP[sbeg + p] = r.x;
        }
    } else if ((int)blockIdx.x < PBK + ABK) {
        // ---- author bucket sort ----
        int t = threadIdx.x, b = (int)blockIdx.x - PBK;
        int x0 = (PBK + b) * NBLK;
        int sbeg = bb[x0] + bsum[x0 >> 8] - E;
        int send;
        if (b == ABK - 1) send = E;    // x0+NBLK would be NBINS (unscanned)
        else { int x1 = x0 + NBLK; send = bb[x1] + bsum[x1 >> 8] - E; }
        for (int i = t; i < 2 * ANB; i += BT) c[i] = 0;
        __syncthreads();
        for (int i = sbeg + t; i < send; i += BT)
            atomicAdd(&c[S_a[i].y], 1);
        __syncthreads();
        int a0 = c[2 * t], a1 = c[2 * t + 1];
        ps[t] = a0 + a1; __syncthreads();
        for (int dlt = 1; dlt < BT; dlt <<= 1) {
            int x = (t >= dlt) ? ps[t - dlt] : 0;
            __syncthreads();
            ps[t] += x;
            __syncthreads();
        }
        int run = ps[t] - a0 - a1;     // exclusive within bucket
        int n0 = (b << (ASH + 1)) + 2 * t;
        loc[2 * t] = run;
        loc[2 * t + 1] = run + a0;
        if (n0 < 2 * NA)     offA[n0]     = sbeg + run;
        if (n0 + 1 < 2 * NA) offA[n0 + 1] = sbeg + run + a0;
        if (b == 0 && t == 0) offA[2 * NA] = E;
        __syncthreads();
        for (int i = sbeg + t; i < send; i += BT) {
            uint2 r = S_a[i];
            int p = atomicAdd(&loc[r.y], 1);
            adjA[sbeg + p] = r.x;
        }
    } else {
        // ---- belief init ----
        __shared__ float sH[72], sCol[4];
        int t = threadIdx.x;
        if (t < 72) sH[t] = Hpa[(t >> 2) * DD + (t & 3)];
        if (t < 4) { float s = 0.f; for (int k = 0; k < DD; ++k) s += Hpa[k * DD + t]; sCol[t] = s; }
        __syncthreads();
        int i = ((int)blockIdx.x - PBK - ABK) * BT + t;
        if (i >= NTot) return;
        if (i < NA) {
            float x[4] = {0.f, 0.f, 0.f, 0.f};
            int m = mask_a[i];
            int l = m ? lab_a[i] : 0;
            if (m) {
                x[0] = x[1] = x[2] = x[3] = -CCF;
                x[l] += (float)DIMA * CCF;
            }
            priorA[i] = m ? (unsigned char)(0x20 | l) : 0;
            Ya[i] = make_ushort4(f2bf(x[0]), f2bf(x[1]), f2bf(x[2]), f2bf(x[3]));
        } else {
            int d = i - NA;
            float z0 = 0.f, z1 = 0.f, z2 = 0.f, z3 = 0.f;
            int m = mask_p[d];
            int l = m ? lab_p[d] : 0;
            if (m) {
                float lb = (float)DD * CCF;
                z0 = -CCF * sCol[0] + lb * sH[l * 4 + 0];
                z1 = -CCF * sCol[1] + lb * sH[l * 4 + 1];
                z2 = -CCF * sCol[2] + lb * sH[l * 4 + 2];
                z3 = -CCF * sCol[3] + lb * sH[l * 4 + 3];
            }
            priorP[d] = m ? (unsigned char)(0x20 | l) : 0;
            Zp[d] = make_ushort4(f2bf(z0), f2bf(z1), f2bf(z2), f2bf(z3));
        }
    }
}

// One fused Jacobi step. Papers: ZpNew = z0 + (gather YaOld) @ M.
// Authors (4 thr/node): YaNew = x0 + SCALEF * (gather ZpOld), dst-half 0
// then 1 so the live Zp working set is ~2MB (L2-resident per XCD).
// ZpNew store skipped on last iter (ZpB lives in d_out).
__global__ __launch_bounds__(256) void gather_iter(
    const int* __restrict__ offP, const int* __restrict__ offA,
    const unsigned int* __restrict__ adjP, const unsigned int* __restrict__ adjA,
    const ushort4* __restrict__ ZpOld, ushort4* __restrict__ ZpNew,
    const ushort4* __restrict__ YaOld, ushort4* __restrict__ YaNew,
    const unsigned char* __restrict__ priorA, const unsigned char* __restrict__ priorP,
    const float* __restrict__ Hap, const float* __restrict__ Hpa,
    float* __restrict__ out, int NP, int NA, int last, int gpB)
{
    if ((int)blockIdx.x < gpB) {
        // ---- papers ----
        __shared__ float sH[72], sCol[4], sM[16], sHap[72];
        int t = threadIdx.x;
        if (t < 72) sH[t] = Hpa[(t >> 2) * DD + (t & 3)];
        if (t < 4) { float s = 0.f; for (int k = 0; k < DD; ++k) s += Hpa[k * DD + t]; sCol[t] = s; }
        if (t < 16) { int i = t >> 2, j = t & 3; float s = 0.f;
                      for (int k = 0; k < DD; ++k) s += Hap[i * DD + k] * Hpa[k * DD + j];
                      sM[t] = SCALEF * s; }
        if (t < 72) sHap[t] = SCALEF * Hap[t];
        __syncthreads();

        int d = (int)blockIdx.x * 256 + t;
        if (d >= NP) return;
        int beg = offP[d], end = offP[d + 1];
        unsigned int pb = priorP[d];   // hoisted off the critical-path tail
        float ax = 0.f, ay = 0.f, az = 0.f, aw = 0.f;
        int s = beg;
        for (; s + 8 <= end; s += 8) {
            unsigned int e0 = adjP[s],     e1 = adjP[s + 1], e2 = adjP[s + 2], e3 = adjP[s + 3];
            unsigned int e4 = adjP[s + 4], e5 = adjP[s + 5], e6 = adjP[s + 6], e7 = adjP[s + 7];
            ushort4 y0 = YaOld[e0 >> 13], y1 = YaOld[e1 >> 13];
            ushort4 y2 = YaOld[e2 >> 13], y3 = YaOld[e3 >> 13];
            ushort4 y4 = YaOld[e4 >> 13], y5 = YaOld[e5 >> 13];
            ushort4 y6 = YaOld[e6 >> 13], y7 = YaOld[e7 >> 13];
            float w0 = w132f(e0 & 0x1fffu), w1 = w132f(e1 & 0x1fffu);
            float w2 = w132f(e2 & 0x1fffu), w3 = w132f(e3 & 0x1fffu);
            float w4 = w132f(e4 & 0x1fffu), w5 = w132f(e5 & 0x1fffu);
            float w6 = w132f(e6 & 0x1fffu), w7 = w132f(e7 & 0x1fffu);
            ax += w0 * bf2f(y0.x) + w1 * bf2f(y1.x) + w2 * bf2f(y2.x) + w3 * bf2f(y3.x)
                + w4 * bf2f(y4.x) + w5 * bf2f(y5.x) + w6 * bf2f(y6.x) + w7 * bf2f(y7.x);
            ay += w0 * bf2f(y0.y) + w1 * bf2f(y1.y) + w2 * bf2f(y2.y) + w3 * bf2f(y3.y)
                + w4 * bf2f(y4.y) + w5 * bf2f(y5.y) + w6 * bf2f(y6.y) + w7 * bf2f(y7.y);
            az += w0 * bf2f(y0.z) + w1 * bf2f(y1.z) + w2 * bf2f(y2.z) + w3 * bf2f(y3.z)
                + w4 * bf2f(y4.z) + w5 * bf2f(y5.z) + w6 * bf2f(y6.z) + w7 * bf2f(y7.z);
            aw += w0 * bf2f(y0.w) + w1 * bf2f(y1.w) + w2 * bf2f(y2.w) + w3 * bf2f(y3.w)
                + w4 * bf2f(y4.w) + w5 * bf2f(y5.w) + w6 * bf2f(y6.w) + w7 * bf2f(y7.w);
        }
        for (; s + 4 <= end; s += 4) {
            unsigned int e0 = adjP[s], e1 = adjP[s + 1], e2 = adjP[s + 2], e3 = adjP[s + 3];
            ushort4 y0 = YaOld[e0 >> 13], y1 = YaOld[e1 >> 13];
            ushort4 y2 = YaOld[e2 >> 13], y3 = YaOld[e3 >> 13];
            float w0 = w132f(e0 & 0x1fffu), w1 = w132f(e1 & 0x1fffu);
            float w2 = w132f(e2 & 0x1fffu), w3 = w132f(e3 & 0x1fffu);
            ax += w0 * bf2f(y0.x) + w1 * bf2f(y1.x) + w2 * bf2f(y2.x) + w3 * bf2f(y3.x);
            ay += w0 * bf2f(y0.y) + w1 * bf2f(y1.y) + w2 * bf2f(y2.y) + w3 * bf2f(y3.y);
            az += w0 * bf2f(y0.z) + w1 * bf2f(y1.z) + w2 * bf2f(y2.z) + w3 * bf2f(y3.z);
            aw += w0 * bf2f(y0.w) + w1 * bf2f(y1.w) + w2 * bf2f(y2.w) + w3 * bf2f(y3.w);
        }
        for (; s < end; ++s) {
            unsigned int ent = adjP[s];
            float wt = w132f(ent & 0x1fffu);
            ushort4 yv = YaOld[ent >> 13];
            ax += wt * bf2f(yv.x); ay += wt * bf2f(yv.y);
            az += wt * bf2f(yv.z); aw += wt * bf2f(yv.w);
        }
        int l = pb & 31;
        float base = pb ? -CCF : 0.f;
        float lb   = pb ? (float)DD * CCF : 0.f;
        if (!last) {
            float z0 = base * sCol[0] + lb * sH[l * 4 + 0] + ax * sM[0] + ay * sM[4] + az * sM[8]  + aw * sM[12];
            float z1 = base * sCol[1] + lb * sH[l * 4 + 1] + ax * sM[1] + ay * sM[5] + az * sM[9]  + aw * sM[13];
            float z2 = base * sCol[2] + lb * sH[l * 4 + 2] + ax * sM[2] + ay * sM[6] + az * sM[10] + aw * sM[14];
            float z3 = base * sCol[3] + lb * sH[l * 4 + 3] + ax * sM[3] + ay * sM[7] + az * sM[11] + aw * sM[15];
            ZpNew[d] = make_ushort4(f2bf(z0), f2bf(z1), f2bf(z2), f2bf(z3));
        } else {
            float* row = out + (size_t)(NA + d) * DD;
#pragma unroll
            for (int j = 0; j < DD; ++j) {
                row[j] = base + ((j == l) ? lb : 0.f)
                       + ax * sHap[0 * DD + j] + ay * sHap[1 * DD + j]
                       + az * sHap[2 * DD + j] + aw * sHap[3 * DD + j];
            }
        }
    } else {
        // ---- authors: 4 threads per node, dst-half 0 then 1, unroll x2 ----
        int tid = ((int)blockIdx.x - gpB) * 256 + threadIdx.x;
        int a = tid >> 2, sub = tid & 3;
        if (a >= NA) return;
        int beg = offA[2 * a], mid = offA[2 * a + 1], end = offA[2 * a + 2];
        unsigned int pb = priorA[a];   // hoisted (uniform per node, L2 hit)
        float ax = 0.f, ay = 0.f, az = 0.f, aw = 0.f;
#pragma unroll
        for (int h = 0; h < 2; ++h) {
            int lo = h ? mid : beg;
            int hi = h ? end : mid;
            int s = lo + sub;
            for (; s + 4 < hi; s += 8) {
                unsigned int e0 = adjA[s], e1 = adjA[s + 4];
                ushort4 z0 = ZpOld[e0 >> 13], z1 = ZpOld[e1 >> 13];
                float w0 = w132f(e0 & 0x1fffu), w1 = w132f(e1 & 0x1fffu);
                ax += w0 * bf2f(z0.x) + w1 * bf2f(z1.x);
                ay += w0 * bf2f(z0.y) + w1 * bf2f(z1.y);
                az += w0 * bf2f(z0.z) + w1 * bf2f(z1.z);
                aw += w0 * bf2f(z0.w) + w1 * bf2f(z1.w);
            }
            for (; s < hi; s += 4) {
                unsigned int ent = adjA[s];
                float wt = w132f(ent & 0x1fffu);
                ushort4 z = ZpOld[ent >> 13];
                ax += wt * bf2f(z.x); ay += wt * bf2f(z.y);
                az += wt * bf2f(z.z); aw += wt * bf2f(z.w);
            }
        }
        ax += __shfl_xor(ax, 1); ay += __shfl_xor(ay, 1);
        az += __shfl_xor(az, 1); aw += __shfl_xor(aw, 1);
        ax += __shfl_xor(ax, 2); ay += __shfl_xor(ay, 2);
        az += __shfl_xor(az, 2); aw += __shfl_xor(aw, 2);
        if (sub == 0) {
            int l = pb & 31;
            float x0 = pb ? ((l == 0) ? ((float)DIMA - 1.f) * CCF : -CCF) : 0.f;
            float x1 = pb ? ((l == 1) ? ((float)DIMA - 1.f) * CCF : -CCF) : 0.f;
            float x2 = pb ? ((l == 2) ? ((float)DIMA - 1.f) * CCF : -CCF) : 0.f;
            float x3 = pb ? ((l == 3) ? ((float)DIMA - 1.f) * CCF : -CCF) : 0.f;
            float y0 = x0 + SCALEF * ax, y1 = x1 + SCALEF * ay;
            float y2 = x2 + SCALEF * az, y3 = x3 + SCALEF * aw;
            YaNew[a] = make_ushort4(f2bf(y0), f2bf(y1), f2bf(y2), f2bf(y3));
            if (last) {
                float* row = out + (size_t)a * DD;
                row[0] = y0; row[1] = y1; row[2] = y2; row[3] = y3;
#pragma unroll
                for (int j = DIMA; j < DD; ++j) row[j] = 0.f;
            }
        }
    }
}

extern "C" void kernel_launch(void* const* d_in, const int* in_sizes, int n_in,
                              void* d_out, int out_size, void* d_ws, size_t ws_size,
                              hipStream_t stream)
{
    const float* H_ap   = (const float*)d_in[0];
    const float* H_pa   = (const float*)d_in[1];
    const float* w      = (const float*)d_in[2];
    const int*   esrc   = (const int*)d_in[3];
    const int*   edst   = (const int*)d_in[4];
    const int*   mask_a = (const int*)d_in[5];
    const int*   lab_a  = (const int*)d_in[6];
    const int*   mask_p = (const int*)d_in[7];
    const int*   lab_p  = (const int*)d_in[8];

    const int E  = in_sizes[2];
    const int NA = in_sizes[5];
    const int NP = in_sizes[7];
    const int NT = NP + NA;
    const int NPH = NP / 2;

    // workspace (~26.6 MB)
    char*  basep = (char*)d_ws;
    size_t o = 0;
    auto alloc = [&](size_t bytes) -> char* {
        o = (o + 15) & ~(size_t)15;
        char* p = basep + o;
        o += bytes;
        return p;
    };
    int*           offP   = (int*)          alloc((size_t)(NP + 1) * sizeof(int));
    int*           offA   = (int*)          alloc((size_t)(2 * NA + 1) * sizeof(int));
    int*           bb     = (int*)          alloc((size_t)(NBINS + 1) * sizeof(int));
    int*           bsum   = (int*)          alloc((size_t)4096 * sizeof(int));
    unsigned int*  adjP   = (unsigned int*) alloc((size_t)E * sizeof(unsigned int));
    unsigned int*  adjA   = (unsigned int*) alloc((size_t)E * sizeof(unsigned int));
    unsigned char* priorP = (unsigned char*)alloc((size_t)NP);
    unsigned char* priorA = (unsigned char*)alloc((size_t)NA);
    ushort4*       YaA    = (ushort4*)      alloc((size_t)NA * sizeof(ushort4));
    ushort4*       YaB    = (ushort4*)      alloc((size_t)NA * sizeof(ushort4));
    ushort4*       ZpA    = (ushort4*)      alloc((size_t)NP * sizeof(ushort4));
    (void)ws_size;

    // S_p (16MB), S_a (16MB), ZpB (4MB) live in d_out (43.2MB): out is
    // written only in the last iteration. Staging dead after csr_all; ZpB
    // written it0/it2, last read it3; ZpNew store skipped when last.
    float*   out = (float*)d_out;
    size_t   sBytes = (((size_t)E * sizeof(uint2)) + 255) & ~(size_t)255;
    uint2*   S_p = (uint2*)d_out;
    uint2*   S_a = (uint2*)((char*)d_out + sBytes);
    ushort4* ZpB = (ushort4*)((char*)d_out + 2 * sBytes);

    ushort4* YaBuf[2] = {YaA, YaB};
    ushort4* ZpBuf[2] = {ZpA, ZpB};

    const int chunk = (E + NBLK - 1) / NBLK;
    const int gp    = (NP + 255) / 256;
    const int ga4   = (NA * 4 + 255) / 256;
    const int gni   = (NT + BT - 1) / BT;
    const int nb    = (NBINS + 255) / 256;        // 1536

    count_bins<<<NBLK, BT, 0, stream>>>(esrc, edst, bb, E, chunk);
    scan_block<<<nb, 256, 0, stream>>>(bb, bsum, NBINS);
    scan_tops<<<1, 256, 0, stream>>>(bsum, nb);
    scat_p<<<NBLK, BT, 0, stream>>>(esrc, edst, w, bb, bsum, S_p, E, chunk);
    scat_a<<<NBLK, BT, 0, stream>>>(esrc, edst, w, bb, bsum, S_a, E, chunk, NPH);
    csr_all<<<PBK + ABK + gni, BT, 0, stream>>>(bb, bsum, S_p, S_a,
                                                adjP, offP, adjA, offA,
                                                mask_a, lab_a, mask_p, lab_p,
                                                H_pa, YaA, ZpA, priorA, priorP,
                                                NP, NA, NT, E);

    for (int it = 0; it < PROP; ++it) {
        int last = (it == PROP - 1) ? 1 : 0;
        int cur = it & 1, nxt = 1 - cur;
        gather_iter<<<gp + ga4, 256, 0, stream>>>(offP, offA, adjP, adjA,
                                                  ZpBuf[cur], ZpBuf[nxt],
                                                  YaBuf[cur], YaBuf[nxt],
                                                  priorA, priorP,
                                                  H_ap, H_pa, out,
                                                  NP, NA, last, gp);
    }
}

// Round 12
// 326.111 us; speedup vs baseline: 1.0473x; 1.0179x over previous
//
#include <hip/hip_runtime.h>

// ZooBP: atomic-free counting-sort CSR build + bf16 double-buffered gathers.
//  - Build: two-level LDS-histogram counting sort, zero global atomics.
//    NBLK=512 edge blocks; paper buckets dst>>10 (512 x 1024), authors src>>9.
//    BT=512 build blocks (16 waves/CU; R9 +21us).
//  - R10/R11 lessons (measured): FUSED scat_pa (stores interleaved into two
//    16MB regions) = 3x write amplification, +20us. csr_all fusion = -4.4us.
//    8 thr/node authors = -10us (decomposed from R10/R11 system; was masked
//    by scat_pa regression and wrongly reverted in R11 -> restored here).
//  - S_p = d_out[0,16MB), S_a = d_out[16,32MB), ZpB = d_out[32,36MB).
//    (d_out 43.2MB written only in last iter; staging dead after csr_all.)
//  - R5/R6 lessons (measured): NT stores = 3.4x write amplification; NT loads
//    = +10us gather (L1 bypass latency). NO non-temporal anything.
//  - R7 (kept): author adjacency split by dst-half; offA[2*NA+1]; author
//    gather walks half 0 then half 1 -> live Zp ~2MB, L2-resident.
//  - adjacency entry = (idx<<13) | w13 (top 13 bits of fp32 w; exact for w=1).

static constexpr int   DD     = 18;
static constexpr int   DIMA   = 4;
static constexpr float CCF    = 0.01f;
static constexpr float SCALEF = 0.1f / 18.0f;
static constexpr int   PROP   = 5;

static constexpr int NBLK  = 512;          // edge-pass blocks
static constexpr int BT    = 512;          // build block threads
static constexpr int PSH   = 10;           // paper bucket shift (1024/bucket)
static constexpr int ASH   = 9;            // author bucket shift (512/bucket)
static constexpr int PBK   = 512;          // paper buckets
static constexpr int ABK   = 256;          // author buckets
static constexpr int PNB   = 1 << PSH;     // 1024 papers per bucket
static constexpr int ANB   = 1 << ASH;     // 512 authors per bucket
static constexpr int NBIN  = PBK + ABK;    // 768
static constexpr int NBINS = NBIN * NBLK;  // 393216 scan elements

__device__ __forceinline__ float bf2f(unsigned short u) {
    return __uint_as_float(((unsigned int)u) << 16);
}
__device__ __forceinline__ unsigned short f2bf(float f) {
    unsigned int x = __float_as_uint(f);
    return (unsigned short)((x + 0x7fffu + ((x >> 16) & 1u)) >> 16);
}
__device__ __forceinline__ unsigned int f2w13(float f) {
    unsigned int x = __float_as_uint(f);
    return ((x + 0x3ffffu + ((x >> 19) & 1u)) >> 19) & 0x1fffu;
}
__device__ __forceinline__ float w132f(unsigned int u) {
    return __uint_as_float(u << 19);
}
// XCD-aware: consecutive logical b share an XCD. NBLK%8==0.
__device__ __forceinline__ int swz_blk() {
    return ((int)blockIdx.x & 7) * (NBLK >> 3) + ((int)blockIdx.x >> 3);
}

// Pass A1: per-block LDS histograms over coarse buckets, both sides at once.
// bb layout: paper bin i -> bb[i*NBLK + b], author bin i -> bb[(PBK+i)*NBLK + b].
__global__ __launch_bounds__(BT) void count_bins(
    const int* __restrict__ esrc, const int* __restrict__ edst,
    int* __restrict__ bb, int E, int chunk)
{
    __shared__ int hP[PBK];
    __shared__ int hA[ABK];
    int t = threadIdx.x, b = swz_blk();
    if (t < PBK) hP[t] = 0;
    if (t < ABK) hA[t] = 0;
    __syncthreads();
    int beg = b * chunk;
    int end = beg + chunk; if (end > E) end = E;
    for (int e = beg + t; e < end; e += BT) {
        atomicAdd(&hP[edst[e] >> PSH], 1);
        atomicAdd(&hA[esrc[e] >> ASH], 1);
    }
    __syncthreads();
    if (t < PBK) bb[t * NBLK + b] = hP[t];
    if (t < ABK) bb[(PBK + t) * NBLK + b] = hA[t];
}

__global__ __launch_bounds__(256) void scan_block(
    int* __restrict__ off, int* __restrict__ bsum, int NT)
{
    __shared__ int s[256];
    int t = threadIdx.x;
    int i = blockIdx.x * 256 + t;
    int v = (i < NT) ? off[i] : 0;
    s[t] = v; __syncthreads();
    for (int dlt = 1; dlt < 256; dlt <<= 1) {
        int x = (t >= dlt) ? s[t - dlt] : 0;
        __syncthreads();
        s[t] += x;
        __syncthreads();
    }
    if (i < NT) off[i] = s[t] - v;
    if (t == 255) bsum[blockIdx.x] = s[255];
}

__global__ __launch_bounds__(256) void scan_tops(int* __restrict__ bsum, int nb)
{
    __shared__ int s[256];
    int t = threadIdx.x;
    int K = (nb + 255) / 256;
    int base = t * K;
    int sum = 0;
    for (int r = 0; r < K; ++r) { int idx = base + r; if (idx < nb) sum += bsum[idx]; }
    s[t] = sum; __syncthreads();
    for (int dlt = 1; dlt < 256; dlt <<= 1) {
        int x = (t >= dlt) ? s[t - dlt] : 0;
        __syncthreads();
        s[t] += x;
        __syncthreads();
    }
    int run = s[t] - sum;
    for (int r = 0; r < K; ++r) {
        int idx = base + r;
        if (idx < nb) { int tmp = bsum[idx]; bsum[idx] = run; run += tmp; }
    }
}

// Pass A3 (papers): scatter staging records using LDS ranks on scanned bases.
// Global exclusive prefix of flat idx = bb[idx] + bsum[idx>>8].
__global__ __launch_bounds__(BT) void scat_p(
    const int* __restrict__ esrc, const int* __restrict__ edst,
    const float* __restrict__ w, const int* __restrict__ bb,
    const int* __restrict__ bsum, uint2* __restrict__ S, int E, int chunk)
{
    __shared__ int base[PBK];
    int t = threadIdx.x, b = swz_blk();
    if (t < PBK) {
        int idx = t * NBLK + b;
        base[t] = bb[idx] + bsum[idx >> 8];
    }
    __syncthreads();
    int beg = b * chunk;
    int end = beg + chunk; if (end > E) end = E;
    for (int e = beg + t; e < end; e += BT) {
        int d = edst[e], s = esrc[e];
        unsigned int rec = ((unsigned int)s << 13) | f2w13(w[e]);
        int pos = atomicAdd(&base[d >> PSH], 1);
        S[pos] = make_uint2(rec, (unsigned int)(d & (PNB - 1)));
    }
}

// Pass A3 (authors): record.x = adjA word (dst<<13|w13),
// record.y = ((src&(ANB-1))<<1) | (dst >= NP/2)  -- dst-half split key.
__global__ __launch_bounds__(BT) void scat_a(
    const int* __restrict__ esrc, const int* __restrict__ edst,
    const float* __restrict__ w, const int* __restrict__ bb,
    const int* __restrict__ bsum, uint2* __restrict__ S, int E, int chunk,
    int NPH)
{
    __shared__ int base[ABK];
    int t = threadIdx.x, b = swz_blk();
    if (t < ABK) {
        int idx = (PBK + t) * NBLK + b;
        base[t] = bb[idx] + bsum[idx >> 8] - E;
    }
    __syncthreads();
    int beg = b * chunk;
    int end = beg + chunk; if (end > E) end = E;
    for (int e = beg + t; e < end; e += BT) {
        int d = edst[e], s = esrc[e];
        unsigned int rec = ((unsigned int)d << 13) | f2w13(w[e]);
        unsigned int key = ((unsigned int)(s & (ANB - 1)) << 1) | (d >= NPH ? 1u : 0u);
        int pos = atomicAdd(&base[s >> ASH], 1);
        S[pos] = make_uint2(rec, key);
    }
}

// Phase B fused: blocks [0,PBK) paper buckets (from S_p); [PBK,PBK+ABK)
// author buckets by (low<<1)|half key (from S_a) -> offA[2*NA+1];
// blocks [PBK+ABK,..) belief init.
__global__ __launch_bounds__(BT) void csr_all(
    const int* __restrict__ bb, const int* __restrict__ bsum,
    const uint2* __restrict__ S_p, const uint2* __restrict__ S_a,
    unsigned int* __restrict__ adjP, int* __restrict__ offP,
    unsigned int* __restrict__ adjA, int* __restrict__ offA,
    const int* __restrict__ mask_a, const int* __restrict__ lab_a,
    const int* __restrict__ mask_p, const int* __restrict__ lab_p,
    const float* __restrict__ Hpa,
    ushort4* __restrict__ Ya, ushort4* __restrict__ Zp,
    unsigned char* __restrict__ priorA, unsigned char* __restrict__ priorP,
    int NP, int NA, int NTot, int E)
{
    __shared__ int c[PNB];         // PNB == 2*ANB == 1024
    __shared__ int loc[PNB];
    __shared__ int ps[BT];
    if ((int)blockIdx.x < PBK) {
        // ---- paper bucket sort ----
        int t = threadIdx.x, b = blockIdx.x;
        int i0 = b * NBLK;
        int i1 = (b + 1) * NBLK;      // b=PBK-1 -> author-region start prefix = E
        int sbeg = bb[i0] + bsum[i0 >> 8];
        int send = bb[i1] + bsum[i1 >> 8];
        for (int i = t; i < PNB; i += BT) c[i] = 0;
        __syncthreads();
        for (int i = sbeg + t; i < send; i += BT)
            atomicAdd(&c[S_p[i].y], 1);
        __syncthreads();
        int a0 = c[2 * t], a1 = c[2 * t + 1];
        ps[t] = a0 + a1; __syncthreads();
        for (int dlt = 1; dlt < BT; dlt <<= 1) {
            int x = (t >= dlt) ? ps[t - dlt] : 0;
            __syncthreads();
            ps[t] += x;
            __syncthreads();
        }
        int run = ps[t] - a0 - a1;     // exclusive within bucket
        int n0 = (b << PSH) + 2 * t;
        loc[2 * t] = run;
        loc[2 * t + 1] = run + a0;
        if (n0 < NP)     offP[n0]     = sbeg + run;
        if (n0 + 1 < NP) offP[n0 + 1] = sbeg + run + a0;
        if (b == 0 && t == 0) offP[NP] = E;
        __syncthreads();
        for (int i = sbeg + t; i < send; i += BT) {
            uint2 r = S_p[i];
            int p = atomicAdd(&loc[r.y], 1);
            adjP[sbeg + p] = r.x;
        }
    } else if ((int)blockIdx.x < PBK + ABK) {
        // ---- author bucket sort ----
        int t = threadIdx.x, b = (int)blockIdx.x - PBK;
        int x0 = (PBK + b) * NBLK;
        int sbeg = bb[x0] + bsum[x0 >> 8] - E;
        int send;
        if (b == ABK - 1) send = E;    // x0+NBLK would be NBINS (unscanned)
        else { int x1 = x0 + NBLK; send = bb[x1] + bsum[x1 >> 8] - E; }
        for (int i = t; i < 2 * ANB; i += BT) c[i] = 0;
        __syncthreads();
        for (int i = sbeg + t; i < send; i += BT)
            atomicAdd(&c[S_a[i].y], 1);
        __syncthreads();
        int a0 = c[2 * t], a1 = c[2 * t + 1];
        ps[t] = a0 + a1; __syncthreads();
        for (int dlt = 1; dlt < BT; dlt <<= 1) {
            int x = (t >= dlt) ? ps[t - dlt] : 0;
            __syncthreads();
            ps[t] += x;
            __syncthreads();
        }
        int run = ps[t] - a0 - a1;     // exclusive within bucket
        int n0 = (b << (ASH + 1)) + 2 * t;
        loc[2 * t] = run;
        loc[2 * t + 1] = run + a0;
        if (n0 < 2 * NA)     offA[n0]     = sbeg + run;
        if (n0 + 1 < 2 * NA) offA[n0 + 1] = sbeg + run + a0;
        if (b == 0 && t == 0) offA[2 * NA] = E;
        __syncthreads();
        for (int i = sbeg + t; i < send; i += BT) {
            uint2 r = S_a[i];
            int p = atomicAdd(&loc[r.y], 1);
            adjA[sbeg + p] = r.x;
        }
    } else {
        // ---- belief init ----
        __shared__ float sH[72], sCol[4];
        int t = threadIdx.x;
        if (t < 72) sH[t] = Hpa[(t >> 2) * DD + (t & 3)];
        if (t < 4) { float s = 0.f; for (int k = 0; k < DD; ++k) s += Hpa[k * DD + t]; sCol[t] = s; }
        __syncthreads();
        int i = ((int)blockIdx.x - PBK - ABK) * BT + t;
        if (i >= NTot) return;
        if (i < NA) {
            float x[4] = {0.f, 0.f, 0.f, 0.f};
            int m = mask_a[i];
            int l = m ? lab_a[i] : 0;
            if (m) {
                x[0] = x[1] = x[2] = x[3] = -CCF;
                x[l] += (float)DIMA * CCF;
            }
            priorA[i] = m ? (unsigned char)(0x20 | l) : 0;
            Ya[i] = make_ushort4(f2bf(x[0]), f2bf(x[1]), f2bf(x[2]), f2bf(x[3]));
        } else {
            int d = i - NA;
            float z0 = 0.f, z1 = 0.f, z2 = 0.f, z3 = 0.f;
            int m = mask_p[d];
            int l = m ? lab_p[d] : 0;
            if (m) {
                float lb = (float)DD * CCF;
                z0 = -CCF * sCol[0] + lb * sH[l * 4 + 0];
                z1 = -CCF * sCol[1] + lb * sH[l * 4 + 1];
                z2 = -CCF * sCol[2] + lb * sH[l * 4 + 2];
                z3 = -CCF * sCol[3] + lb * sH[l * 4 + 3];
            }
            priorP[d] = m ? (unsigned char)(0x20 | l) : 0;
            Zp[d] = make_ushort4(f2bf(z0), f2bf(z1), f2bf(z2), f2bf(z3));
        }
    }
}

// One fused Jacobi step. Papers: ZpNew = z0 + (gather YaOld) @ M.
// Authors (8 thr/node): YaNew = x0 + SCALEF * (gather ZpOld), dst-half 0
// then 1 so the live Zp working set is ~2MB (L2-resident per XCD).
// ZpNew store skipped on last iter (ZpB lives in d_out).
__global__ __launch_bounds__(256) void gather_iter(
    const int* __restrict__ offP, const int* __restrict__ offA,
    const unsigned int* __restrict__ adjP, const unsigned int* __restrict__ adjA,
    const ushort4* __restrict__ ZpOld, ushort4* __restrict__ ZpNew,
    const ushort4* __restrict__ YaOld, ushort4* __restrict__ YaNew,
    const unsigned char* __restrict__ priorA, const unsigned char* __restrict__ priorP,
    const float* __restrict__ Hap, const float* __restrict__ Hpa,
    float* __restrict__ out, int NP, int NA, int last, int gpB)
{
    if ((int)blockIdx.x < gpB) {
        // ---- papers ----
        __shared__ float sH[72], sCol[4], sM[16], sHap[72];
        int t = threadIdx.x;
        if (t < 72) sH[t] = Hpa[(t >> 2) * DD + (t & 3)];
        if (t < 4) { float s = 0.f; for (int k = 0; k < DD; ++k) s += Hpa[k * DD + t]; sCol[t] = s; }
        if (t < 16) { int i = t >> 2, j = t & 3; float s = 0.f;
                      for (int k = 0; k < DD; ++k) s += Hap[i * DD + k] * Hpa[k * DD + j];
                      sM[t] = SCALEF * s; }
        if (t < 72) sHap[t] = SCALEF * Hap[t];
        __syncthreads();

        int d = (int)blockIdx.x * 256 + t;
        if (d >= NP) return;
        int beg = offP[d], end = offP[d + 1];
        unsigned int pb = priorP[d];   // hoisted off the critical-path tail
        float ax = 0.f, ay = 0.f, az = 0.f, aw = 0.f;
        int s = beg;
        for (; s + 8 <= end; s += 8) {
            unsigned int e0 = adjP[s],     e1 = adjP[s + 1], e2 = adjP[s + 2], e3 = adjP[s + 3];
            unsigned int e4 = adjP[s + 4], e5 = adjP[s + 5], e6 = adjP[s + 6], e7 = adjP[s + 7];
            ushort4 y0 = YaOld[e0 >> 13], y1 = YaOld[e1 >> 13];
            ushort4 y2 = YaOld[e2 >> 13], y3 = YaOld[e3 >> 13];
            ushort4 y4 = YaOld[e4 >> 13], y5 = YaOld[e5 >> 13];
            ushort4 y6 = YaOld[e6 >> 13], y7 = YaOld[e7 >> 13];
            float w0 = w132f(e0 & 0x1fffu), w1 = w132f(e1 & 0x1fffu);
            float w2 = w132f(e2 & 0x1fffu), w3 = w132f(e3 & 0x1fffu);
            float w4 = w132f(e4 & 0x1fffu), w5 = w132f(e5 & 0x1fffu);
            float w6 = w132f(e6 & 0x1fffu), w7 = w132f(e7 & 0x1fffu);
            ax += w0 * bf2f(y0.x) + w1 * bf2f(y1.x) + w2 * bf2f(y2.x) + w3 * bf2f(y3.x)
                + w4 * bf2f(y4.x) + w5 * bf2f(y5.x) + w6 * bf2f(y6.x) + w7 * bf2f(y7.x);
            ay += w0 * bf2f(y0.y) + w1 * bf2f(y1.y) + w2 * bf2f(y2.y) + w3 * bf2f(y3.y)
                + w4 * bf2f(y4.y) + w5 * bf2f(y5.y) + w6 * bf2f(y6.y) + w7 * bf2f(y7.y);
            az += w0 * bf2f(y0.z) + w1 * bf2f(y1.z) + w2 * bf2f(y2.z) + w3 * bf2f(y3.z)
                + w4 * bf2f(y4.z) + w5 * bf2f(y5.z) + w6 * bf2f(y6.z) + w7 * bf2f(y7.z);
            aw += w0 * bf2f(y0.w) + w1 * bf2f(y1.w) + w2 * bf2f(y2.w) + w3 * bf2f(y3.w)
                + w4 * bf2f(y4.w) + w5 * bf2f(y5.w) + w6 * bf2f(y6.w) + w7 * bf2f(y7.w);
        }
        for (; s + 4 <= end; s += 4) {
            unsigned int e0 = adjP[s], e1 = adjP[s + 1], e2 = adjP[s + 2], e3 = adjP[s + 3];
            ushort4 y0 = YaOld[e0 >> 13], y1 = YaOld[e1 >> 13];
            ushort4 y2 = YaOld[e2 >> 13], y3 = YaOld[e3 >> 13];
            float w0 = w132f(e0 & 0x1fffu), w1 = w132f(e1 & 0x1fffu);
            float w2 = w132f(e2 & 0x1fffu), w3 = w132f(e3 & 0x1fffu);
            ax += w0 * bf2f(y0.x) + w1 * bf2f(y1.x) + w2 * bf2f(y2.x) + w3 * bf2f(y3.x);
            ay += w0 * bf2f(y0.y) + w1 * bf2f(y1.y) + w2 * bf2f(y2.y) + w3 * bf2f(y3.y);
            az += w0 * bf2f(y0.z) + w1 * bf2f(y1.z) + w2 * bf2f(y2.z) + w3 * bf2f(y3.z);
            aw += w0 * bf2f(y0.w) + w1 * bf2f(y1.w) + w2 * bf2f(y2.w) + w3 * bf2f(y3.w);
        }
        for (; s < end; ++s) {
            unsigned int ent = adjP[s];
            float wt = w132f(ent & 0x1fffu);
            ushort4 yv = YaOld[ent >> 13];
            ax += wt * bf2f(yv.x); ay += wt * bf2f(yv.y);
            az += wt * bf2f(yv.z); aw += wt * bf2f(yv.w);
        }
        int l = pb & 31;
        float base = pb ? -CCF : 0.f;
        float lb   = pb ? (float)DD * CCF : 0.f;
        if (!last) {
            float z0 = base * sCol[0] + lb * sH[l * 4 + 0] + ax * sM[0] + ay * sM[4] + az * sM[8]  + aw * sM[12];
            float z1 = base * sCol[1] + lb * sH[l * 4 + 1] + ax * sM[1] + ay * sM[5] + az * sM[9]  + aw * sM[13];
            float z2 = base * sCol[2] + lb * sH[l * 4 + 2] + ax * sM[2] + ay * sM[6] + az * sM[10] + aw * sM[14];
            float z3 = base * sCol[3] + lb * sH[l * 4 + 3] + ax * sM[3] + ay * sM[7] + az * sM[11] + aw * sM[15];
            ZpNew[d] = make_ushort4(f2bf(z0), f2bf(z1), f2bf(z2), f2bf(z3));
        } else {
            float* row = out + (size_t)(NA + d) * DD;
#pragma unroll
            for (int j = 0; j < DD; ++j) {
                row[j] = base + ((j == l) ? lb : 0.f)
                       + ax * sHap[0 * DD + j] + ay * sHap[1 * DD + j]
                       + az * sHap[2 * DD + j] + aw * sHap[3 * DD + j];
            }
        }
    } else {
        // ---- authors: 8 threads per node, dst-half 0 then 1, unroll x2 ----
        int tid = ((int)blockIdx.x - gpB) * 256 + threadIdx.x;
        int a = tid >> 3, sub = tid & 7;
        if (a >= NA) return;
        int beg = offA[2 * a], mid = offA[2 * a + 1], end = offA[2 * a + 2];
        unsigned int pb = priorA[a];   // hoisted (uniform per node, L2 hit)
        float ax = 0.f, ay = 0.f, az = 0.f, aw = 0.f;
#pragma unroll
        for (int h = 0; h < 2; ++h) {
            int lo = h ? mid : beg;
            int hi = h ? end : mid;
            int s = lo + sub;
            for (; s + 8 < hi; s += 16) {
                unsigned int e0 = adjA[s], e1 = adjA[s + 8];
                ushort4 z0 = ZpOld[e0 >> 13], z1 = ZpOld[e1 >> 13];
                float w0 = w132f(e0 & 0x1fffu), w1 = w132f(e1 & 0x1fffu);
                ax += w0 * bf2f(z0.x) + w1 * bf2f(z1.x);
                ay += w0 * bf2f(z0.y) + w1 * bf2f(z1.y);
                az += w0 * bf2f(z0.z) + w1 * bf2f(z1.z);
                aw += w0 * bf2f(z0.w) + w1 * bf2f(z1.w);
            }
            for (; s < hi; s += 8) {
                unsigned int ent = adjA[s];
                float wt = w132f(ent & 0x1fffu);
                ushort4 z = ZpOld[ent >> 13];
                ax += wt * bf2f(z.x); ay += wt * bf2f(z.y);
                az += wt * bf2f(z.z); aw += wt * bf2f(z.w);
            }
        }
        ax += __shfl_xor(ax, 1); ay += __shfl_xor(ay, 1);
        az += __shfl_xor(az, 1); aw += __shfl_xor(aw, 1);
        ax += __shfl_xor(ax, 2); ay += __shfl_xor(ay, 2);
        az += __shfl_xor(az, 2); aw += __shfl_xor(aw, 2);
        ax += __shfl_xor(ax, 4); ay += __shfl_xor(ay, 4);
        az += __shfl_xor(az, 4); aw += __shfl_xor(aw, 4);
        if (sub == 0) {
            int l = pb & 31;
            float x0 = pb ? ((l == 0) ? ((float)DIMA - 1.f) * CCF : -CCF) : 0.f;
            float x1 = pb ? ((l == 1) ? ((float)DIMA - 1.f) * CCF : -CCF) : 0.f;
            float x2 = pb ? ((l == 2) ? ((float)DIMA - 1.f) * CCF : -CCF) : 0.f;
            float x3 = pb ? ((l == 3) ? ((float)DIMA - 1.f) * CCF : -CCF) : 0.f;
            float y0 = x0 + SCALEF * ax, y1 = x1 + SCALEF * ay;
            float y2 = x2 + SCALEF * az, y3 = x3 + SCALEF * aw;
            YaNew[a] = make_ushort4(f2bf(y0), f2bf(y1), f2bf(y2), f2bf(y3));
            if (last) {
                float* row = out + (size_t)a * DD;
                row[0] = y0; row[1] = y1; row[2] = y2; row[3] = y3;
#pragma unroll
                for (int j = DIMA; j < DD; ++j) row[j] = 0.f;
            }
        }
    }
}

extern "C" void kernel_launch(void* const* d_in, const int* in_sizes, int n_in,
                              void* d_out, int out_size, void* d_ws, size_t ws_size,
                              hipStream_t stream)
{
    const float* H_ap   = (const float*)d_in[0];
    const float* H_pa   = (const float*)d_in[1];
    const float* w      = (const float*)d_in[2];
    const int*   esrc   = (const int*)d_in[3];
    const int*   edst   = (const int*)d_in[4];
    const int*   mask_a = (const int*)d_in[5];
    const int*   lab_a  = (const int*)d_in[6];
    const int*   mask_p = (const int*)d_in[7];
    const int*   lab_p  = (const int*)d_in[8];

    const int E  = in_sizes[2];
    const int NA = in_sizes[5];
    const int NP = in_sizes[7];
    const int NT = NP + NA;
    const int NPH = NP / 2;

    // workspace (~26.6 MB)
    char*  basep = (char*)d_ws;
    size_t o = 0;
    auto alloc = [&](size_t bytes) -> char* {
        o = (o + 15) & ~(size_t)15;
        char* p = basep + o;
        o += bytes;
        return p;
    };
    int*           offP   = (int*)          alloc((size_t)(NP + 1) * sizeof(int));
    int*           offA   = (int*)          alloc((size_t)(2 * NA + 1) * sizeof(int));
    int*           bb     = (int*)          alloc((size_t)(NBINS + 1) * sizeof(int));
    int*           bsum   = (int*)          alloc((size_t)4096 * sizeof(int));
    unsigned int*  adjP   = (unsigned int*) alloc((size_t)E * sizeof(unsigned int));
    unsigned int*  adjA   = (unsigned int*) alloc((size_t)E * sizeof(unsigned int));
    unsigned char* priorP = (unsigned char*)alloc((size_t)NP);
    unsigned char* priorA = (unsigned char*)alloc((size_t)NA);
    ushort4*       YaA    = (ushort4*)      alloc((size_t)NA * sizeof(ushort4));
    ushort4*       YaB    = (ushort4*)      alloc((size_t)NA * sizeof(ushort4));
    ushort4*       ZpA    = (ushort4*)      alloc((size_t)NP * sizeof(ushort4));
    (void)ws_size;

    // S_p (16MB), S_a (16MB), ZpB (4MB) live in d_out (43.2MB): out is
    // written only in the last iteration. Staging dead after csr_all; ZpB
    // written it0/it2, last read it3; ZpNew store skipped when last.
    float*   out = (float*)d_out;
    size_t   sBytes = (((size_t)E * sizeof(uint2)) + 255) & ~(size_t)255;
    uint2*   S_p = (uint2*)d_out;
    uint2*   S_a = (uint2*)((char*)d_out + sBytes);
    ushort4* ZpB = (ushort4*)((char*)d_out + 2 * sBytes);

    ushort4* YaBuf[2] = {YaA, YaB};
    ushort4* ZpBuf[2] = {ZpA, ZpB};

    const int chunk = (E + NBLK - 1) / NBLK;
    const int gp    = (NP + 255) / 256;
    const int ga8   = (NA * 8 + 255) / 256;
    const int gni   = (NT + BT - 1) / BT;
    const int nb    = (NBINS + 255) / 256;        // 1536

    count_bins<<<NBLK, BT, 0, stream>>>(esrc, edst, bb, E, chunk);
    scan_block<<<nb, 256, 0, stream>>>(bb, bsum, NBINS);
    scan_tops<<<1, 256, 0, stream>>>(bsum, nb);
    scat_p<<<NBLK, BT, 0, stream>>>(esrc, edst, w, bb, bsum, S_p, E, chunk);
    scat_a<<<NBLK, BT, 0, stream>>>(esrc, edst, w, bb, bsum, S_a, E, chunk, NPH);
    csr_all<<<PBK + ABK + gni, BT, 0, stream>>>(bb, bsum, S_p, S_a,
                                                adjP, offP, adjA, offA,
                                                mask_a, lab_a, mask_p, lab_p,
                                                H_pa, YaA, ZpA, priorA, priorP,
                                                NP, NA, NT, E);

    for (int it = 0; it < PROP; ++it) {
        int last = (it == PROP - 1) ? 1 : 0;
        int cur = it & 1, nxt = 1 - cur;
        gather_iter<<<gp + ga8, 256, 0, stream>>>(offP, offA, adjP, adjA,
                                                  ZpBuf[cur], ZpBuf[nxt],
                                                  YaBuf[cur], YaBuf[nxt],
                                                  priorA, priorP,
                                                  H_ap, H_pa, out,
                                                  NP, NA, last, gp);
    }
}